// Round 3
// baseline (741.661 us; speedup 1.0000x reference)
//
#include <hip/hip_runtime.h>
#include <hip/hip_bf16.h>
#include <stdint.h>

#define IN_F   4096
#define OUT_F  4096
#define BATCH  4096

typedef __bf16 bf16x8_t __attribute__((ext_vector_type(8)));
typedef float  f32x4_t  __attribute__((ext_vector_type(4)));

// ---------------------------------------------------------------------------
// Fully fused: y = x @ (W .* M)^T + b in ONE kernel, no workspace.
//   - A-staging: load x fp32 -> cvt bf16 (RNE, identical to prior hand-rne)
//   - B-staging: load w,m fp32 -> w*m -> cvt bf16
//   - reg-staging (global->reg->LDS) replaces global_load_lds so conversion
//     happens in flight; LDS write goes to the SAME XOR-swizzled slot the
//     proven read path expects (slot = chunk ^ (row&7)); read path unchanged.
//   - one barrier per K-step, double-buffered; next-tile loads issued at top
//     of iter, consumed (cvt+ds_write) after compute -> full-tile flight.
//   - XCD-bijective block swizzle (1024 % 8 == 0): fp32+mask staging triples
//     beyond-L1 traffic, so L2 locality matters more than before.
// Math is bit-identical to the previous 3-kernel version.
// (Round 2: byte-identical resubmission — round-1 bench died to container
//  infra failure, not kernel fault; see journal for the audit.)
// ---------------------------------------------------------------------------
#define BM 128
#define BN 128
#define BK 64

__global__ __launch_bounds__(256, 2)
void fused_gemm_kernel(const float* __restrict__ x,     // [BATCH][IN_F]
                       const float* __restrict__ w,     // [OUT_F][IN_F]
                       const float* __restrict__ bias,  // [OUT_F]
                       const float* __restrict__ m,     // [OUT_F][IN_F]
                       float* __restrict__ C) {         // [BATCH][OUT_F]
    __shared__ __align__(16) unsigned short sA[2][BM * BK];  // 2 x 16 KiB
    __shared__ __align__(16) unsigned short sB[2][BN * BK];  // 2 x 16 KiB

    const int t    = threadIdx.x;
    const int wv   = t >> 6;
    const int lane = t & 63;
    const int quad = lane >> 4;    // 0..3
    const int l16  = lane & 15;

    // XCD-aware bijective swizzle: 1024 blocks, 8 XCDs -> each XCD gets a
    // contiguous 128-tile chunk (4 full M-rows of the 32x32 tile grid).
    const int bid = blockIdx.x;
    const int swz = (bid & 7) * 128 + (bid >> 3);   // bijective on [0,1024)
    const int bx  = swz & 31;                       // N tile
    const int by  = swz >> 5;                       // M tile
    const int bm  = by * BM;
    const int bn  = bx * BN;

    const int wr = wv >> 1;
    const int wc = wv & 1;

    // Staging coords: round r of 4 covers rows r*32 + (t>>3); thread t owns
    // k-chunk c8 = t&7 (8 elements = 32 B fp32 / 16 B bf16).
    const int srow = t >> 3;     // 0..31
    const int c8   = t & 7;
    const float* gx = x + (int64_t)(bm + srow) * IN_F + c8 * 8;
    const float* gw = w + (int64_t)(bn + srow) * IN_F + c8 * 8;
    const float* gm = m + (int64_t)(bn + srow) * IN_F + c8 * 8;

    // LDS byte offset (per round add r*4096): row*128 B + swizzled slot*16 B.
    // row&7 == srow&7 since r*32 is 0 mod 8. Read path expects chunk c at
    // slot c ^ (row&7) -- write side mirrors it exactly.
    const int ldsoff = srow * 128 + ((c8 ^ (srow & 7)) * 16);

    f32x4_t rx[4][2], rw[4][2], rm[4][2];   // next-tile staging regs (96 VGPR)

#define LOAD_TILE(k0)                                                         \
    do {                                                                      \
        _Pragma("unroll")                                                     \
        for (int r = 0; r < 4; ++r) {                                         \
            const float* px = gx + (int64_t)r * 32 * IN_F + (k0);             \
            const float* pw = gw + (int64_t)r * 32 * IN_F + (k0);             \
            const float* pm = gm + (int64_t)r * 32 * IN_F + (k0);             \
            rx[r][0] = *(const f32x4_t*)(px);                                 \
            rx[r][1] = *(const f32x4_t*)(px + 4);                             \
            rw[r][0] = *(const f32x4_t*)(pw);                                 \
            rw[r][1] = *(const f32x4_t*)(pw + 4);                             \
            rm[r][0] = *(const f32x4_t*)(pm);                                 \
            rm[r][1] = *(const f32x4_t*)(pm + 4);                             \
        }                                                                     \
    } while (0)

#define CVT_WRITE(bufi)                                                       \
    do {                                                                      \
        _Pragma("unroll")                                                     \
        for (int r = 0; r < 4; ++r) {                                         \
            bf16x8_t va, vb;                                                  \
            _Pragma("unroll")                                                 \
            for (int j = 0; j < 4; ++j) {                                     \
                va[j]     = (__bf16)rx[r][0][j];                              \
                va[j + 4] = (__bf16)rx[r][1][j];                              \
                vb[j]     = (__bf16)(rw[r][0][j] * rm[r][0][j]);              \
                vb[j + 4] = (__bf16)(rw[r][1][j] * rm[r][1][j]);              \
            }                                                                 \
            *(bf16x8_t*)((char*)sA[bufi] + r * 4096 + ldsoff) = va;           \
            *(bf16x8_t*)((char*)sB[bufi] + r * 4096 + ldsoff) = vb;           \
        }                                                                     \
    } while (0)

    f32x4_t acc[4][4];
#pragma unroll
    for (int mi = 0; mi < 4; ++mi)
#pragma unroll
        for (int ni = 0; ni < 4; ++ni)
            acc[mi][ni] = (f32x4_t){0.f, 0.f, 0.f, 0.f};

    // Prologue: stage tile 0.
    LOAD_TILE(0);
    CVT_WRITE(0);

    int buf = 0;
    for (int k0 = 0; k0 < IN_F; k0 += BK, buf ^= 1) {
        // One barrier per iter: (a) makes this-iter's sA/sB[buf] ds_writes
        // (issued end of last iter / prologue) visible to all waves,
        // (b) guarantees everyone finished reading buf^1 last iter, so the
        // CVT_WRITE(buf^1) at the END of this iter is race-free.
        __syncthreads();

        if (k0 + BK < IN_F)
            LOAD_TILE(k0 + BK);          // vmem flight spans the compute below

        const unsigned short* __restrict__ cA = sA[buf];
        const unsigned short* __restrict__ cB = sB[buf];

#pragma unroll
        for (int ks = 0; ks < 2; ++ks) {
            bf16x8_t af[4], bfr[4];
#pragma unroll
            for (int mi = 0; mi < 4; ++mi) {
                const int row = wr * 64 + mi * 16 + l16;
                const int ch  = (ks * 4 + quad) ^ (row & 7);
                af[mi] = *(const bf16x8_t*)(cA + row * BK + ch * 8);
            }
#pragma unroll
            for (int ni = 0; ni < 4; ++ni) {
                const int row = wc * 64 + ni * 16 + l16;
                const int ch  = (ks * 4 + quad) ^ (row & 7);
                bfr[ni] = *(const bf16x8_t*)(cB + row * BK + ch * 8);
            }
#pragma unroll
            for (int mi = 0; mi < 4; ++mi)
#pragma unroll
                for (int ni = 0; ni < 4; ++ni)
                    acc[mi][ni] = __builtin_amdgcn_mfma_f32_16x16x32_bf16(
                        af[mi], bfr[ni], acc[mi][ni], 0, 0, 0);
        }

        if (k0 + BK < IN_F)
            CVT_WRITE(buf ^ 1);          // waits vmcnt on rx/rw/rm, writes LDS
    }

    // Epilogue: C/D layout col = lane&15 (n), row = quad*4 + reg (m).
    float bv[4];
#pragma unroll
    for (int ni = 0; ni < 4; ++ni)
        bv[ni] = bias[bn + wc * 64 + ni * 16 + l16];

#pragma unroll
    for (int mi = 0; mi < 4; ++mi) {
        const int row0 = bm + wr * 64 + mi * 16 + quad * 4;
#pragma unroll
        for (int ni = 0; ni < 4; ++ni) {
            const int col = bn + wc * 64 + ni * 16 + l16;
#pragma unroll
            for (int reg = 0; reg < 4; ++reg)
                C[(int64_t)(row0 + reg) * OUT_F + col] = acc[mi][ni][reg] + bv[ni];
        }
    }
#undef LOAD_TILE
#undef CVT_WRITE
}

// ---------------------------------------------------------------------------
extern "C" void kernel_launch(void* const* d_in, const int* in_sizes, int n_in,
                              void* d_out, int out_size, void* d_ws, size_t ws_size,
                              hipStream_t stream) {
    const float* x    = (const float*)d_in[0];
    const float* w    = (const float*)d_in[1];
    const float* bias = (const float*)d_in[2];
    const float* m    = (const float*)d_in[3];
    float* y = (float*)d_out;

    (void)d_ws; (void)ws_size;  // workspace intentionally unused (suspect slow)

    fused_gemm_kernel<<<1024, 256, 0, stream>>>(x, w, bias, m, y);
}

// Round 4
// 326.734 us; speedup vs baseline: 2.2699x; 2.2699x over previous
//
#include <hip/hip_runtime.h>
#include <hip/hip_bf16.h>
#include <stdint.h>

#define IN_F   4096
#define OUT_F  4096
#define BATCH  4096

typedef __bf16 bf16x8_t __attribute__((ext_vector_type(8)));
typedef float  f32x4_t  __attribute__((ext_vector_type(4)));
typedef float  f32x4v   __attribute__((ext_vector_type(4)));
typedef unsigned short u16x4v __attribute__((ext_vector_type(4)));

#define AS_GLOBAL(p) ((const __attribute__((address_space(1))) void*)(p))
#define AS_LDS(p)    ((__attribute__((address_space(3))) void*)(p))

__device__ __forceinline__ unsigned short f32_to_bf16_rne(float f) {
    union { float f; uint32_t u; } v; v.f = f;
    uint32_t u = v.u;
    u += 0x7FFFu + ((u >> 16) & 1u);
    return (unsigned short)(u >> 16);
}

// ---------------------------------------------------------------------------
// Pre-pass (round-0 proven verbatim): xb = bf16(x), wb = bf16(W * M).
// ---------------------------------------------------------------------------
__global__ __launch_bounds__(256)
void convert_kernel(const float* __restrict__ x,
                    const float* __restrict__ w,
                    const float* __restrict__ m,
                    unsigned short* __restrict__ xb,
                    unsigned short* __restrict__ wb) {
    const int64_t i0 = (int64_t)blockIdx.x * 512 + threadIdx.x;
#pragma unroll
    for (int u = 0; u < 2; ++u) {
        const int64_t i = i0 + u * 256;
        f32x4v xv = __builtin_nontemporal_load(&((const f32x4v*)x)[i]);
        f32x4v wv = __builtin_nontemporal_load(&((const f32x4v*)w)[i]);
        f32x4v mv = __builtin_nontemporal_load(&((const f32x4v*)m)[i]);
        u16x4v xo, wo;
        xo.x = f32_to_bf16_rne(xv.x);
        xo.y = f32_to_bf16_rne(xv.y);
        xo.z = f32_to_bf16_rne(xv.z);
        xo.w = f32_to_bf16_rne(xv.w);
        wo.x = f32_to_bf16_rne(wv.x * mv.x);
        wo.y = f32_to_bf16_rne(wv.y * mv.y);
        wo.z = f32_to_bf16_rne(wv.z * mv.z);
        wo.w = f32_to_bf16_rne(wv.w * mv.w);
        ((u16x4v*)xb)[i] = xo;
        ((u16x4v*)wb)[i] = wo;
    }
}

// ---------------------------------------------------------------------------
// 8-phase 256x256 GEMM (T2+T3+T4+T5), BK=64, 512 thr (8 waves = 2M x 4N),
// LDS 128 KiB: sA/sB[dbuf][half][128x64]. Per wave: 128x64 output,
// 24 ds_read_b128 + 64 MFMA per K-tile, in 4 phases (16 MFMA each).
// Stage schedule (race-free by retire analysis):
//   B-halves of dbuf d retire at P1's closing barrier; A-halves at P2's.
//   P0 issues (T+1,A1); P2 issues (T+2,B0); P3 issues (T+2,B1),(T+2,A0).
//   Gate per tile: vmcnt(6) [= 3 newest half-tile stages in flight] + barrier.
// Accumulation order per acc unchanged vs round-0 kernel -> bit-identical y.
// ---------------------------------------------------------------------------
#define BM 256
#define BN 256
#define BK 64
#define NT (IN_F / BK)   // 64

__global__ __launch_bounds__(512, 2)
void gemm_8phase_kernel(const unsigned short* __restrict__ A,   // [BATCH][IN_F]
                        const unsigned short* __restrict__ B,   // [OUT_F][IN_F]
                        const float* __restrict__ bias,
                        float* __restrict__ C) {
    __shared__ __align__(16) unsigned short sA[2][2][128 * 64];  // 64 KiB
    __shared__ __align__(16) unsigned short sB[2][2][128 * 64];  // 64 KiB

    const int t    = threadIdx.x;
    const int wv   = t >> 6;        // 0..7
    const int lane = t & 63;
    const int quad = lane >> 4;     // 0..3
    const int l16  = lane & 15;
    const int wr   = wv >> 2;       // 0..1 (M)
    const int wc   = wv & 3;        // 0..3 (N)
    const int bhalf = wc >> 1;      // which B half this wave reads
    const int brow0 = (wc & 1) * 64;

    // XCD-aware bijective swizzle over 256 blocks (256 % 8 == 0).
    const int bid = blockIdx.x;
    const int swz = (bid & 7) * 32 + (bid >> 3);
    const int bm  = (swz >> 4) * BM;
    const int bn  = (swz & 15) * BN;

    // Staging: thread t loads 16 B chunks; row-in-half = rr*64 + (t>>3),
    // source k-chunk pre-swizzled by row&7 so LDS stays linear (rule 21).
    const int srow = t >> 3;                        // 0..63
    const int scol = 8 * ((t & 7) ^ (srow & 7));    // elements
    const unsigned short* gA = A + (int64_t)(bm + srow) * IN_F + scol;
    const unsigned short* gB = B + (int64_t)(bn + srow) * IN_F + scol;
    const int ldsoff = t * 16;                      // wv*1024 + lane*16

#define STAGE_A(TT, h)                                                        \
    do {                                                                      \
        _Pragma("unroll")                                                     \
        for (int rr = 0; rr < 2; ++rr)                                        \
            __builtin_amdgcn_global_load_lds(                                 \
                AS_GLOBAL(gA + (int64_t)((h) * 128 + rr * 64) * IN_F + (TT) * BK), \
                AS_LDS((char*)sA[(TT) & 1][h] + rr * 8192 + ldsoff), 16, 0, 0); \
    } while (0)
#define STAGE_B(TT, h)                                                        \
    do {                                                                      \
        _Pragma("unroll")                                                     \
        for (int rr = 0; rr < 2; ++rr)                                        \
            __builtin_amdgcn_global_load_lds(                                 \
                AS_GLOBAL(gB + (int64_t)((h) * 128 + rr * 64) * IN_F + (TT) * BK), \
                AS_LDS((char*)sB[(TT) & 1][h] + rr * 8192 + ldsoff), 16, 0, 0); \
    } while (0)

    f32x4_t acc[8][4];
#pragma unroll
    for (int mi = 0; mi < 8; ++mi)
#pragma unroll
        for (int ni = 0; ni < 4; ++ni)
            acc[mi][ni] = (f32x4_t){0.f, 0.f, 0.f, 0.f};

    // Prologue: tile 0 fully + 3 halves of tile 1 (mimics steady-state order).
    STAGE_A(0, 0); STAGE_A(0, 1); STAGE_B(0, 0); STAGE_B(0, 1);
    STAGE_B(1, 0); STAGE_B(1, 1); STAGE_A(1, 0);
    asm volatile("s_waitcnt vmcnt(6)" ::: "memory");  // tile 0 landed
    __builtin_amdgcn_s_barrier();

    for (int T = 0; T < NT; ++T) {
        const unsigned short* myA = sA[T & 1][wr];
        const unsigned short* myB = sB[T & 1][bhalf];

        bf16x8_t af[4][2], bf0[2][2], bf1[2][2];

        // ------------- P0: read af(mi0-3)+bf(ni0-1); stage (T+1,A1) -------
#pragma unroll
        for (int j = 0; j < 4; ++j) {
            const int row = j * 16 + l16;
#pragma unroll
            for (int ks = 0; ks < 2; ++ks)
                af[j][ks] = *(const bf16x8_t*)(myA + row * 64 +
                                ((ks * 4 + quad) ^ (row & 7)) * 8);
        }
#pragma unroll
        for (int j = 0; j < 2; ++j) {
            const int row = brow0 + j * 16 + l16;
#pragma unroll
            for (int ks = 0; ks < 2; ++ks)
                bf0[j][ks] = *(const bf16x8_t*)(myB + row * 64 +
                                ((ks * 4 + quad) ^ (row & 7)) * 8);
        }
        if (T + 1 < NT) STAGE_A(T + 1, 1);
        __builtin_amdgcn_s_barrier();
        asm volatile("s_waitcnt lgkmcnt(0)" ::: "memory");
        __builtin_amdgcn_s_setprio(1);
#pragma unroll
        for (int mi = 0; mi < 4; ++mi)
#pragma unroll
            for (int ni = 0; ni < 2; ++ni)
#pragma unroll
                for (int ks = 0; ks < 2; ++ks)
                    acc[mi][ni] = __builtin_amdgcn_mfma_f32_16x16x32_bf16(
                        af[mi][ks], bf0[ni][ks], acc[mi][ni], 0, 0, 0);
        __builtin_amdgcn_s_setprio(0);
        __builtin_amdgcn_s_barrier();

        // ------------- P1: read bf(ni2-3); mfma mi0-3 x ni2-3 -------------
#pragma unroll
        for (int j = 0; j < 2; ++j) {
            const int row = brow0 + (j + 2) * 16 + l16;
#pragma unroll
            for (int ks = 0; ks < 2; ++ks)
                bf1[j][ks] = *(const bf16x8_t*)(myB + row * 64 +
                                ((ks * 4 + quad) ^ (row & 7)) * 8);
        }
        __builtin_amdgcn_s_barrier();
        asm volatile("s_waitcnt lgkmcnt(0)" ::: "memory");
        __builtin_amdgcn_s_setprio(1);
#pragma unroll
        for (int mi = 0; mi < 4; ++mi)
#pragma unroll
            for (int ni = 0; ni < 2; ++ni)
#pragma unroll
                for (int ks = 0; ks < 2; ++ks)
                    acc[mi][ni + 2] = __builtin_amdgcn_mfma_f32_16x16x32_bf16(
                        af[mi][ks], bf1[ni][ks], acc[mi][ni + 2], 0, 0, 0);
        __builtin_amdgcn_s_setprio(0);
        __builtin_amdgcn_s_barrier();
        // B-halves of this dbuf retired (all waves past P1's barrier).

        // ------------- P2: read af(mi4-7); stage (T+2,B0); mfma mi4-7 x ni2-3
#pragma unroll
        for (int j = 0; j < 4; ++j) {
            const int row = (j + 4) * 16 + l16;
#pragma unroll
            for (int ks = 0; ks < 2; ++ks)
                af[j][ks] = *(const bf16x8_t*)(myA + row * 64 +
                                ((ks * 4 + quad) ^ (row & 7)) * 8);
        }
        if (T + 2 < NT) STAGE_B(T + 2, 0);
        __builtin_amdgcn_s_barrier();
        asm volatile("s_waitcnt lgkmcnt(0)" ::: "memory");
        __builtin_amdgcn_s_setprio(1);
#pragma unroll
        for (int mi = 0; mi < 4; ++mi)
#pragma unroll
            for (int ni = 0; ni < 2; ++ni)
#pragma unroll
                for (int ks = 0; ks < 2; ++ks)
                    acc[mi + 4][ni + 2] = __builtin_amdgcn_mfma_f32_16x16x32_bf16(
                        af[mi][ks], bf1[ni][ks], acc[mi + 4][ni + 2], 0, 0, 0);
        __builtin_amdgcn_s_setprio(0);
        __builtin_amdgcn_s_barrier();
        // A-halves of this dbuf retired.

        // ------------- P3: stage (T+2,B1),(T+2,A0); mfma mi4-7 x ni0-1;
        //               gate tile T+1 with counted vmcnt ------------------
        if (T + 2 < NT) { STAGE_B(T + 2, 1); STAGE_A(T + 2, 0); }
        __builtin_amdgcn_s_barrier();
        __builtin_amdgcn_s_setprio(1);
#pragma unroll
        for (int mi = 0; mi < 4; ++mi)
#pragma unroll
            for (int ni = 0; ni < 2; ++ni)
#pragma unroll
                for (int ks = 0; ks < 2; ++ks)
                    acc[mi + 4][ni] = __builtin_amdgcn_mfma_f32_16x16x32_bf16(
                        af[mi][ks], bf0[ni][ks], acc[mi + 4][ni], 0, 0, 0);
        __builtin_amdgcn_s_setprio(0);
        if (T < NT - 2)
            asm volatile("s_waitcnt vmcnt(6)" ::: "memory");
        else if (T < NT - 1)
            asm volatile("s_waitcnt vmcnt(0)" ::: "memory");
        __builtin_amdgcn_s_barrier();
    }

    // Epilogue: C/D layout col = lane&15 (n), row = quad*4 + reg (m).
    float bv[4];
#pragma unroll
    for (int ni = 0; ni < 4; ++ni)
        bv[ni] = bias[bn + wc * 64 + ni * 16 + l16];

#pragma unroll
    for (int mi = 0; mi < 8; ++mi) {
        const int row0 = bm + wr * 128 + mi * 16 + quad * 4;
#pragma unroll
        for (int ni = 0; ni < 4; ++ni) {
            const int col = bn + wc * 64 + ni * 16 + l16;
#pragma unroll
            for (int reg = 0; reg < 4; ++reg)
                C[(int64_t)(row0 + reg) * OUT_F + col] = acc[mi][ni][reg] + bv[ni];
        }
    }
#undef STAGE_A
#undef STAGE_B
}

// ---------------------------------------------------------------------------
// Fallback (workspace too small): plain fp32 tiled GEMM.
// ---------------------------------------------------------------------------
__global__ void fallback_gemm_kernel(const float* __restrict__ x,
                                     const float* __restrict__ w,
                                     const float* __restrict__ bias,
                                     const float* __restrict__ m,
                                     float* __restrict__ y) {
    __shared__ float sx[16][17];
    __shared__ float sw[16][17];
    const int tx = threadIdx.x, ty = threadIdx.y;
    const int row = blockIdx.y * 16 + ty;
    const int col = blockIdx.x * 16 + tx;
    float acc = 0.f;
    for (int k0 = 0; k0 < IN_F; k0 += 16) {
        sx[ty][tx] = x[(int64_t)row * IN_F + k0 + tx];
        const int64_t widx = (int64_t)(blockIdx.x * 16 + ty) * IN_F + k0 + tx;
        sw[ty][tx] = w[widx] * m[widx];
        __syncthreads();
#pragma unroll
        for (int kk = 0; kk < 16; ++kk)
            acc += sx[ty][kk] * sw[tx][kk];
        __syncthreads();
    }
    y[(int64_t)row * OUT_F + col] = acc + bias[col];
}

// ---------------------------------------------------------------------------
extern "C" void kernel_launch(void* const* d_in, const int* in_sizes, int n_in,
                              void* d_out, int out_size, void* d_ws, size_t ws_size,
                              hipStream_t stream) {
    const float* x    = (const float*)d_in[0];
    const float* w    = (const float*)d_in[1];
    const float* bias = (const float*)d_in[2];
    const float* m    = (const float*)d_in[3];
    float* y = (float*)d_out;

    const size_t need = (size_t)2 * (size_t)OUT_F * (size_t)IN_F * sizeof(unsigned short);

    if (ws_size >= need) {
        unsigned short* xb = (unsigned short*)d_ws;
        unsigned short* wb = xb + (size_t)BATCH * IN_F;

        convert_kernel<<<8192, 256, 0, stream>>>(x, w, m, xb, wb);

        gemm_8phase_kernel<<<256, 512, 0, stream>>>(xb, wb, bias, y);
    } else {
        dim3 grid(OUT_F / 16, BATCH / 16);
        dim3 block(16, 16);
        fallback_gemm_kernel<<<grid, block, 0, stream>>>(x, w, bias, m, y);
    }
}

// Round 5
// 310.248 us; speedup vs baseline: 2.3905x; 1.0531x over previous
//
#include <hip/hip_runtime.h>
#include <hip/hip_bf16.h>
#include <stdint.h>

#define IN_F   4096
#define OUT_F  4096
#define BATCH  4096

typedef __bf16 bf16x8_t __attribute__((ext_vector_type(8)));
typedef float  f32x4_t  __attribute__((ext_vector_type(4)));
typedef float  f32x4v   __attribute__((ext_vector_type(4)));
typedef unsigned short u16x4v __attribute__((ext_vector_type(4)));

#define AS_GLOBAL(p) ((const __attribute__((address_space(1))) void*)(p))
#define AS_LDS(p)    ((__attribute__((address_space(3))) void*)(p))

__device__ __forceinline__ unsigned short f32_to_bf16_rne(float f) {
    union { float f; uint32_t u; } v; v.f = f;
    uint32_t u = v.u;
    u += 0x7FFFu + ((u >> 16) & 1u);
    return (unsigned short)(u >> 16);
}

// ---------------------------------------------------------------------------
// Pre-pass (round-0 proven verbatim): xb = bf16(x), wb = bf16(W * M).
// ---------------------------------------------------------------------------
__global__ __launch_bounds__(256)
void convert_kernel(const float* __restrict__ x,
                    const float* __restrict__ w,
                    const float* __restrict__ m,
                    unsigned short* __restrict__ xb,
                    unsigned short* __restrict__ wb) {
    const int64_t i0 = (int64_t)blockIdx.x * 512 + threadIdx.x;
#pragma unroll
    for (int u = 0; u < 2; ++u) {
        const int64_t i = i0 + u * 256;
        f32x4v xv = __builtin_nontemporal_load(&((const f32x4v*)x)[i]);
        f32x4v wv = __builtin_nontemporal_load(&((const f32x4v*)w)[i]);
        f32x4v mv = __builtin_nontemporal_load(&((const f32x4v*)m)[i]);
        u16x4v xo, wo;
        xo.x = f32_to_bf16_rne(xv.x);
        xo.y = f32_to_bf16_rne(xv.y);
        xo.z = f32_to_bf16_rne(xv.z);
        xo.w = f32_to_bf16_rne(xv.w);
        wo.x = f32_to_bf16_rne(wv.x * mv.x);
        wo.y = f32_to_bf16_rne(wv.y * mv.y);
        wo.z = f32_to_bf16_rne(wv.z * mv.z);
        wo.w = f32_to_bf16_rne(wv.w * mv.w);
        ((u16x4v*)xb)[i] = xo;
        ((u16x4v*)wb)[i] = wo;
    }
}

// ---------------------------------------------------------------------------
// 256x256 GEMM, BK=64, 512 thr (8 waves = 2M x 4N), LDS 128 KiB dbuf.
// Round-5 restructure: the round-4 8-barrier lockstep serialized LDS reads
// against MFMA (measured 5440 cyc/tile ~= 2300 LDS + 2480 MFMA + barriers).
// Now TWO barriers per tile:
//   [tile start, dbuf T&1 valid]
//   issue reads af0,b0,b1 (16) + stage (T+1,A1); Q0,Q1 MFMA;
//   issue reads af1 (8, reusing af regs); Q2,Q3 MFMA;
//   barrier#1  (all waves' reads of dbuf T&1 retired -> safe to overwrite)
//   stage (T+2,B0),(T+2,B1),(T+2,A0)
//   vmcnt(6)   (counted: drains exactly tile T+1's 4 half-tiles)
//   barrier#2  (publish tile T+1)
// Compiler emits fine-grained counted lgkmcnt between ds_read and MFMA
// (m97-verified behavior) -> LDS service overlaps MFMA within the tile.
// Quadrant order Q0..Q3 identical to round 4 -> bit-identical accumulation.
// ---------------------------------------------------------------------------
#define BM 256
#define BN 256
#define BK 64
#define NT (IN_F / BK)   // 64

__global__ __launch_bounds__(512, 2)
void gemm_2bar_kernel(const unsigned short* __restrict__ A,   // [BATCH][IN_F]
                      const unsigned short* __restrict__ B,   // [OUT_F][IN_F]
                      const float* __restrict__ bias,
                      float* __restrict__ C) {
    __shared__ __align__(16) unsigned short sA[2][2][128 * 64];  // 64 KiB
    __shared__ __align__(16) unsigned short sB[2][2][128 * 64];  // 64 KiB

    const int t    = threadIdx.x;
    const int wv   = t >> 6;        // 0..7
    const int lane = t & 63;
    const int quad = lane >> 4;     // 0..3
    const int l16  = lane & 15;
    const int wr   = wv >> 2;       // 0..1 (M half)
    const int wc   = wv & 3;        // 0..3 (N quarter)
    const int bhalf = wc >> 1;      // which B half this wave reads
    const int brow0 = (wc & 1) * 64;

    // XCD-aware bijective swizzle over 256 blocks (256 % 8 == 0).
    const int bid = blockIdx.x;
    const int swz = (bid & 7) * 32 + (bid >> 3);
    const int bm  = (swz >> 4) * BM;
    const int bn  = (swz & 15) * BN;

    // Staging: thread t loads 16 B; row-in-half = rr*64 + (t>>3), source
    // k-chunk pre-swizzled by row&7 so LDS stays linear (rule 21).
    const int srow = t >> 3;                        // 0..63
    const int scol = 8 * ((t & 7) ^ (srow & 7));    // elements
    const unsigned short* gA = A + (int64_t)(bm + srow) * IN_F + scol;
    const unsigned short* gB = B + (int64_t)(bn + srow) * IN_F + scol;
    const int ldsoff = t * 16;

#define STAGE_A(TT, h)                                                        \
    do {                                                                      \
        _Pragma("unroll")                                                     \
        for (int rr = 0; rr < 2; ++rr)                                        \
            __builtin_amdgcn_global_load_lds(                                 \
                AS_GLOBAL(gA + (int64_t)((h) * 128 + rr * 64) * IN_F + (TT) * BK), \
                AS_LDS((char*)sA[(TT) & 1][h] + rr * 8192 + ldsoff), 16, 0, 0); \
    } while (0)
#define STAGE_B(TT, h)                                                        \
    do {                                                                      \
        _Pragma("unroll")                                                     \
        for (int rr = 0; rr < 2; ++rr)                                        \
            __builtin_amdgcn_global_load_lds(                                 \
                AS_GLOBAL(gB + (int64_t)((h) * 128 + rr * 64) * IN_F + (TT) * BK), \
                AS_LDS((char*)sB[(TT) & 1][h] + rr * 8192 + ldsoff), 16, 0, 0); \
    } while (0)

    f32x4_t acc[8][4];
#pragma unroll
    for (int mi = 0; mi < 8; ++mi)
#pragma unroll
        for (int ni = 0; ni < 4; ++ni)
            acc[mi][ni] = (f32x4_t){0.f, 0.f, 0.f, 0.f};

    // Prologue: tile 0 fully + 3 halves of tile 1 (steady-state invariant:
    // after the gate, outstanding = (T+1,B0),(T+1,B1),(T+1,A0) = 6 loads).
    STAGE_A(0, 0); STAGE_A(0, 1); STAGE_B(0, 0); STAGE_B(0, 1);
    STAGE_B(1, 0); STAGE_B(1, 1); STAGE_A(1, 0);
    asm volatile("s_waitcnt vmcnt(6)" ::: "memory");  // tile 0 landed
    __builtin_amdgcn_s_barrier();
    __builtin_amdgcn_sched_barrier(0);

    for (int T = 0; T < NT; ++T) {
        const unsigned short* myA = sA[T & 1][wr];
        const unsigned short* myB = sB[T & 1][bhalf];

        bf16x8_t af[4][2], b0[2][2], b1[2][2];

        // Reads for Q0/Q1 (af rows 0-63 of this wave's A-half, both B subtiles)
#pragma unroll
        for (int j = 0; j < 4; ++j) {
            const int row = j * 16 + l16;
#pragma unroll
            for (int ks = 0; ks < 2; ++ks)
                af[j][ks] = *(const bf16x8_t*)(myA + row * 64 +
                                ((ks * 4 + quad) ^ (row & 7)) * 8);
        }
#pragma unroll
        for (int j = 0; j < 2; ++j) {
            const int row = brow0 + j * 16 + l16;
#pragma unroll
            for (int ks = 0; ks < 2; ++ks)
                b0[j][ks] = *(const bf16x8_t*)(myB + row * 64 +
                                ((ks * 4 + quad) ^ (row & 7)) * 8);
        }
#pragma unroll
        for (int j = 0; j < 2; ++j) {
            const int row = brow0 + (j + 2) * 16 + l16;
#pragma unroll
            for (int ks = 0; ks < 2; ++ks)
                b1[j][ks] = *(const bf16x8_t*)(myB + row * 64 +
                                ((ks * 4 + quad) ^ (row & 7)) * 8);
        }
        if (T + 1 < NT) STAGE_A(T + 1, 1);   // dbuf^1 A1: readers retired last tile

        __builtin_amdgcn_s_setprio(1);
#pragma unroll
        for (int mi = 0; mi < 4; ++mi)       // Q0: acc[0-3][0-1]
#pragma unroll
            for (int ni = 0; ni < 2; ++ni)
#pragma unroll
                for (int ks = 0; ks < 2; ++ks)
                    acc[mi][ni] = __builtin_amdgcn_mfma_f32_16x16x32_bf16(
                        af[mi][ks], b0[ni][ks], acc[mi][ni], 0, 0, 0);
#pragma unroll
        for (int mi = 0; mi < 4; ++mi)       // Q1: acc[0-3][2-3]
#pragma unroll
            for (int ni = 0; ni < 2; ++ni)
#pragma unroll
                for (int ks = 0; ks < 2; ++ks)
                    acc[mi][ni + 2] = __builtin_amdgcn_mfma_f32_16x16x32_bf16(
                        af[mi][ks], b1[ni][ks], acc[mi][ni + 2], 0, 0, 0);
        __builtin_amdgcn_s_setprio(0);

        // Reads for Q2/Q3 (af rows 64-127), reusing af registers (keeps the
        // staging-register peak at round-4's level; issue can still slot
        // between Q1's MFMAs since only WAR on af).
#pragma unroll
        for (int j = 0; j < 4; ++j) {
            const int row = (j + 4) * 16 + l16;
#pragma unroll
            for (int ks = 0; ks < 2; ++ks)
                af[j][ks] = *(const bf16x8_t*)(myA + row * 64 +
                                ((ks * 4 + quad) ^ (row & 7)) * 8);
        }

        __builtin_amdgcn_s_setprio(1);
#pragma unroll
        for (int mi = 0; mi < 4; ++mi)       // Q2: acc[4-7][2-3]
#pragma unroll
            for (int ni = 0; ni < 2; ++ni)
#pragma unroll
                for (int ks = 0; ks < 2; ++ks)
                    acc[mi + 4][ni + 2] = __builtin_amdgcn_mfma_f32_16x16x32_bf16(
                        af[mi][ks], b1[ni][ks], acc[mi + 4][ni + 2], 0, 0, 0);
#pragma unroll
        for (int mi = 0; mi < 4; ++mi)       // Q3: acc[4-7][0-1]
#pragma unroll
            for (int ni = 0; ni < 2; ++ni)
#pragma unroll
                for (int ks = 0; ks < 2; ++ks)
                    acc[mi + 4][ni] = __builtin_amdgcn_mfma_f32_16x16x32_bf16(
                        af[mi][ks], b0[ni][ks], acc[mi + 4][ni], 0, 0, 0);
        __builtin_amdgcn_s_setprio(0);

        if (T + 1 < NT) {
            // barrier#1: every wave has consumed all its reads of dbuf T&1
            // (compiler-inserted lgkmcnt before Q2/Q3 guarantees the wave's
            // own reads completed) -> safe to overwrite dbuf regions below.
            __builtin_amdgcn_s_barrier();
            __builtin_amdgcn_sched_barrier(0);
            if (T + 2 < NT) { STAGE_B(T + 2, 0); STAGE_B(T + 2, 1); STAGE_A(T + 2, 0); }
            if (T < NT - 2)
                asm volatile("s_waitcnt vmcnt(6)" ::: "memory");   // tile T+1 landed
            else
                asm volatile("s_waitcnt vmcnt(0)" ::: "memory");   // drain tail
            // barrier#2: publish tile T+1 to all waves.
            __builtin_amdgcn_s_barrier();
            __builtin_amdgcn_sched_barrier(0);
        }
    }

    // Epilogue: C/D layout col = lane&15 (n), row = quad*4 + reg (m).
    float bv[4];
#pragma unroll
    for (int ni = 0; ni < 4; ++ni)
        bv[ni] = bias[bn + wc * 64 + ni * 16 + l16];

#pragma unroll
    for (int mi = 0; mi < 8; ++mi) {
        const int row0 = bm + wr * 128 + mi * 16 + quad * 4;
#pragma unroll
        for (int ni = 0; ni < 4; ++ni) {
            const int col = bn + wc * 64 + ni * 16 + l16;
#pragma unroll
            for (int reg = 0; reg < 4; ++reg)
                C[(int64_t)(row0 + reg) * OUT_F + col] = acc[mi][ni][reg] + bv[ni];
        }
    }
#undef STAGE_A
#undef STAGE_B
}

// ---------------------------------------------------------------------------
// Fallback (workspace too small): plain fp32 tiled GEMM.
// ---------------------------------------------------------------------------
__global__ void fallback_gemm_kernel(const float* __restrict__ x,
                                     const float* __restrict__ w,
                                     const float* __restrict__ bias,
                                     const float* __restrict__ m,
                                     float* __restrict__ y) {
    __shared__ float sx[16][17];
    __shared__ float sw[16][17];
    const int tx = threadIdx.x, ty = threadIdx.y;
    const int row = blockIdx.y * 16 + ty;
    const int col = blockIdx.x * 16 + tx;
    float acc = 0.f;
    for (int k0 = 0; k0 < IN_F; k0 += 16) {
        sx[ty][tx] = x[(int64_t)row * IN_F + k0 + tx];
        const int64_t widx = (int64_t)(blockIdx.x * 16 + ty) * IN_F + k0 + tx;
        sw[ty][tx] = w[widx] * m[widx];
        __syncthreads();
#pragma unroll
        for (int kk = 0; kk < 16; ++kk)
            acc += sx[ty][kk] * sw[tx][kk];
        __syncthreads();
    }
    y[(int64_t)row * OUT_F + col] = acc + bias[col];
}

// ---------------------------------------------------------------------------
extern "C" void kernel_launch(void* const* d_in, const int* in_sizes, int n_in,
                              void* d_out, int out_size, void* d_ws, size_t ws_size,
                              hipStream_t stream) {
    const float* x    = (const float*)d_in[0];
    const float* w    = (const float*)d_in[1];
    const float* bias = (const float*)d_in[2];
    const float* m    = (const float*)d_in[3];
    float* y = (float*)d_out;

    const size_t need = (size_t)2 * (size_t)OUT_F * (size_t)IN_F * sizeof(unsigned short);

    if (ws_size >= need) {
        unsigned short* xb = (unsigned short*)d_ws;
        unsigned short* wb = xb + (size_t)BATCH * IN_F;

        convert_kernel<<<8192, 256, 0, stream>>>(x, w, m, xb, wb);

        gemm_2bar_kernel<<<256, 512, 0, stream>>>(xb, wb, bias, y);
    } else {
        dim3 grid(OUT_F / 16, BATCH / 16);
        dim3 block(16, 16);
        fallback_gemm_kernel<<<grid, block, 0, stream>>>(x, w, bias, m, y);
    }
}